// Round 10
// baseline (271.665 us; speedup 1.0000x reference)
//
#include <hip/hip_runtime.h>
#include <hip/hip_bf16.h>

typedef float    f4v    __attribute__((ext_vector_type(4)));
typedef short    short8 __attribute__((ext_vector_type(8)));
typedef unsigned u2v    __attribute__((ext_vector_type(2)));

constexpr int Bn = 4096, TR = 16;

// ---- split-bf16 helpers ----------------------------------------------------
__device__ inline unsigned cvt2(float x, float y) {
  union { __hip_bfloat162 h; unsigned u; } c;
  c.h = __float22bfloat162_rn(float2{x, y});
  return c.u;   // low16 = bf16(x), high16 = bf16(y)
}
__device__ inline void split_pair(float x, float y, unsigned& hp, unsigned& lp) {
  hp = cvt2(x, y);
  float hx = __uint_as_float(hp << 16);
  float hy = __uint_as_float(hp & 0xffff0000u);
  lp = cvt2(x - hx, y - hy);
}
union S8U { unsigned u[4]; short8 s; };
__device__ inline void split8(const float v[8], short8& hi, short8& lo) {
  S8U h, l;
  #pragma unroll
  for (int d = 0; d < 4; ++d) split_pair(v[2 * d], v[2 * d + 1], h.u[d], l.u[d]);
  hi = h.s; lo = l.s;
}
__device__ inline void split8p(const float* p, short8& hi, short8& lo) {
  f4v a = *(const f4v*)p, b = *(const f4v*)(p + 4);
  float v[8] = {a[0], a[1], a[2], a[3], b[0], b[1], b[2], b[3]};
  split8(v, hi, lo);
}
__device__ inline f4v mfma16(short8 a, short8 b, f4v c) {
  return __builtin_amdgcn_mfma_f32_16x16x32_bf16(a, b, c, 0, 0, 0);
}
__device__ __attribute__((always_inline)) inline f4v gdot8(
    const short8 (&ah)[8], const short8 (&al)[8],
    const short8 (&bh)[8], const short8 (&bl)[8]) {
  f4v c = {0.f, 0.f, 0.f, 0.f};
  #pragma unroll
  for (int s = 0; s < 8; ++s) {
    c = mfma16(ah[s], bh[s], c);
    c = mfma16(al[s], bh[s], c);
    c = mfma16(ah[s], bl[s], c);
  }
  return c;
}

// ---------------------------------------------------------------------------
// k_prep: KAT[n][m] = (inv(A A^T + 1e-6 I) @ A)^T -> d_ws. 1 block, 256 thr.
// (R8-verified: G via MFMA, Gauss-Jordan on wave 0 via unrolled shuffles.)
// ---------------------------------------------------------------------------
__global__ __launch_bounds__(256) void k_prep(const float* __restrict__ A,
                                              float* __restrict__ KAT) {
  __shared__ __align__(16) float As[32 * 256];
  __shared__ float Gm[32 * 68];
  __shared__ float GinvL[32 * 32];

  const int t = threadIdx.x;
  const int lane = t & 63, wv = t >> 6, quad = lane >> 4, l15 = lane & 15;
  const int T = wv & 1, kh = wv >> 1;

  for (int i = t; i < 2048; i += 256)
    ((f4v*)As)[i] = ((const f4v*)A)[i];
  __syncthreads();

  {
    short8 afh[2][8], afl[2][8];
    #pragma unroll
    for (int tt = 0; tt < 2; ++tt)
      #pragma unroll
      for (int s = 0; s < 8; ++s)
        split8p(As + (l15 + 16 * tt) * 256 + 32 * s + 8 * quad,
                afh[tt][s], afl[tt][s]);
    f4v cg;
    if      (wv == 0) cg = gdot8(afh[0], afl[0], afh[0], afl[0]);
    else if (wv == 1) cg = gdot8(afh[1], afl[1], afh[0], afl[0]);
    else if (wv == 2) cg = gdot8(afh[0], afl[0], afh[1], afl[1]);
    else              cg = gdot8(afh[1], afl[1], afh[1], afl[1]);
    #pragma unroll
    for (int r = 0; r < 4; ++r) {
      int gi = 16 * T + 4 * quad + r, gj = 16 * kh + l15;
      Gm[gi * 68 + gj]      = cg[r] + (gi == gj ? 1e-6f : 0.f);
      Gm[gi * 68 + 32 + gj] = (gi == gj) ? 1.f : 0.f;
    }
  }
  __syncthreads();

  if (wv == 0) {
    float gcol[32];
    #pragma unroll
    for (int i = 0; i < 32; ++i) gcol[i] = Gm[i * 68 + lane];
    #pragma unroll
    for (int k = 0; k < 32; ++k) {
      float ckk  = __shfl(gcol[k], k);
      float ipiv = 1.f / ckk;
      float pivj = gcol[k] * ipiv;
      gcol[k] = pivj;
      #pragma unroll
      for (int i = 0; i < 32; ++i) {
        if (i == k) continue;
        float cki = __shfl(gcol[i], k);
        gcol[i] = fmaf(-cki, pivj, gcol[i]);
      }
    }
    if (lane >= 32) {
      #pragma unroll
      for (int i = 0; i < 32; ++i) GinvL[i * 32 + (lane - 32)] = gcol[i];
    }
  }
  __syncthreads();

  {
    float res[32];
    #pragma unroll
    for (int m = 0; m < 32; ++m) res[m] = 0.f;
    for (int p = 0; p < 32; ++p) {
      float av = As[p * 256 + t];
      #pragma unroll
      for (int m4 = 0; m4 < 8; ++m4) {
        f4v g = *(const f4v*)&GinvL[p * 32 + 4 * m4];
        res[4 * m4 + 0] = fmaf(av, g[0], res[4 * m4 + 0]);
        res[4 * m4 + 1] = fmaf(av, g[1], res[4 * m4 + 1]);
        res[4 * m4 + 2] = fmaf(av, g[2], res[4 * m4 + 2]);
        res[4 * m4 + 3] = fmaf(av, g[3], res[4 * m4 + 3]);
      }
    }
    #pragma unroll
    for (int m4 = 0; m4 < 8; ++m4) {
      f4v v = {res[4 * m4], res[4 * m4 + 1], res[4 * m4 + 2], res[4 * m4 + 3]};
      *(f4v*)&KAT[t * 32 + 4 * m4] = v;
    }
  }
}

// ---------------------------------------------------------------------------
// k_main: 256 threads (4 waves), TR=16, grid 256.  ONE barrier per iteration.
// Each wave: full-K r = A z^T - b (48 MFMA, redundant across waves) ->
// wave-PRIVATE fp32 LDS round-trip (no barrier) -> w for its 4 U-tiles
// (12 MFMA) -> z update in regs -> publish z to dbuf zfrag -> barrier.
// ---------------------------------------------------------------------------
__global__ __launch_bounds__(256, 1) void k_main(
    const float* __restrict__ x,  const float* __restrict__ bmat,
    const float* __restrict__ W1, const float* __restrict__ b1,
    const float* __restrict__ W2, const float* __restrict__ b2,
    const float* __restrict__ W3, const float* __restrict__ b3,
    const float* __restrict__ A,  const float* __restrict__ KAT,
    const int* __restrict__ n_iter_p, float* __restrict__ out) {

  // smem[0..8768): MLP scratch, then overlaid by zfrag dbuf (8192 dwords).
  // smem[8768..11328): wave-private rbuf (4 x 640 floats).
  __shared__ __align__(16) float smem[11328];

  const int t = threadIdx.x;
  const int lane = t & 63, wv = t >> 6, quad = lane >> 4, l15 = lane & 15;
  const int row0 = blockIdx.x * TR;

  float* xs = smem;            // [16][132]
  float* h1 = smem + 2112;     // [16][208]
  float* h2 = smem + 5440;     // [16][208]
  float* ys = smem;            // [16][260] (xs+h1 dead by then)
  unsigned* zsm = (unsigned*)smem;      // zfrag dbuf: 2 x 4096 dwords
  float* rb = smem + 8768 + wv * 640;   // wave-private r: [16 i][36]

  {
    int r = t >> 4, c8 = t & 15;
    *(f4v*)&xs[r * 132 + 8 * c8]     = *(const f4v*)&x[(size_t)(row0 + r) * 128 + 8 * c8];
    *(f4v*)&xs[r * 132 + 8 * c8 + 4] = *(const f4v*)&x[(size_t)(row0 + r) * 128 + 8 * c8 + 4];
  }
  __syncthreads();

  // ---- MLP: 4 rows per wave (R3-verified register-blocked form) ----
  {
    const int rg = wv, oc = lane;
    const bool g3 = (oc < 8);    // HID=200: col oc+192 valid iff oc<8
    float acc[4][4];

    // L1: 128 -> 200, relu
    #pragma unroll
    for (int oi = 0; oi < 4; ++oi)
      #pragma unroll
      for (int r = 0; r < 4; ++r) acc[oi][r] = 0.f;
    for (int k4 = 0; k4 < 32; ++k4) {
      float xv[4][4];
      #pragma unroll
      for (int r = 0; r < 4; ++r) {
        f4v v = *(const f4v*)&xs[(4 * rg + r) * 132 + 4 * k4];
        xv[r][0] = v[0]; xv[r][1] = v[1]; xv[r][2] = v[2]; xv[r][3] = v[3];
      }
      #pragma unroll
      for (int kk = 0; kk < 4; ++kk) {
        const float* wr = W1 + (4 * k4 + kk) * 200 + oc;
        float w0 = wr[0], w1c = wr[64], w2c = wr[128];
        float w3c = g3 ? wr[192] : 0.f;
        #pragma unroll
        for (int r = 0; r < 4; ++r) {
          acc[0][r] = fmaf(xv[r][kk], w0, acc[0][r]);
          acc[1][r] = fmaf(xv[r][kk], w1c, acc[1][r]);
          acc[2][r] = fmaf(xv[r][kk], w2c, acc[2][r]);
          acc[3][r] = fmaf(xv[r][kk], w3c, acc[3][r]);
        }
      }
    }
    #pragma unroll
    for (int oi = 0; oi < 4; ++oi) {
      if (oi == 3 && !g3) continue;
      float bb = b1[oc + 64 * oi];
      #pragma unroll
      for (int r = 0; r < 4; ++r)
        h1[(4 * rg + r) * 208 + oc + 64 * oi] = fmaxf(acc[oi][r] + bb, 0.f);
    }
    __syncthreads();

    // L2: 200 -> 200, relu
    #pragma unroll
    for (int oi = 0; oi < 4; ++oi)
      #pragma unroll
      for (int r = 0; r < 4; ++r) acc[oi][r] = 0.f;
    for (int k4 = 0; k4 < 50; ++k4) {
      float xv[4][4];
      #pragma unroll
      for (int r = 0; r < 4; ++r) {
        f4v v = *(const f4v*)&h1[(4 * rg + r) * 208 + 4 * k4];
        xv[r][0] = v[0]; xv[r][1] = v[1]; xv[r][2] = v[2]; xv[r][3] = v[3];
      }
      #pragma unroll
      for (int kk = 0; kk < 4; ++kk) {
        const float* wr = W2 + (4 * k4 + kk) * 200 + oc;
        float w0 = wr[0], w1c = wr[64], w2c = wr[128];
        float w3c = g3 ? wr[192] : 0.f;
        #pragma unroll
        for (int r = 0; r < 4; ++r) {
          acc[0][r] = fmaf(xv[r][kk], w0, acc[0][r]);
          acc[1][r] = fmaf(xv[r][kk], w1c, acc[1][r]);
          acc[2][r] = fmaf(xv[r][kk], w2c, acc[2][r]);
          acc[3][r] = fmaf(xv[r][kk], w3c, acc[3][r]);
        }
      }
    }
    #pragma unroll
    for (int oi = 0; oi < 4; ++oi) {
      if (oi == 3 && !g3) continue;
      float bb = b2[oc + 64 * oi];
      #pragma unroll
      for (int r = 0; r < 4; ++r)
        h2[(4 * rg + r) * 208 + oc + 64 * oi] = fmaxf(acc[oi][r] + bb, 0.f);
    }
    __syncthreads();

    // L3: 200 -> 256 (no relu) -> ys
    #pragma unroll
    for (int oi = 0; oi < 4; ++oi)
      #pragma unroll
      for (int r = 0; r < 4; ++r) acc[oi][r] = 0.f;
    for (int k4 = 0; k4 < 50; ++k4) {
      float xv[4][4];
      #pragma unroll
      for (int r = 0; r < 4; ++r) {
        f4v v = *(const f4v*)&h2[(4 * rg + r) * 208 + 4 * k4];
        xv[r][0] = v[0]; xv[r][1] = v[1]; xv[r][2] = v[2]; xv[r][3] = v[3];
      }
      #pragma unroll
      for (int kk = 0; kk < 4; ++kk) {
        const float* wr = W3 + (4 * k4 + kk) * 256 + oc;
        float w0 = wr[0], w1c = wr[64], w2c = wr[128], w3c = wr[192];
        #pragma unroll
        for (int r = 0; r < 4; ++r) {
          acc[0][r] = fmaf(xv[r][kk], w0, acc[0][r]);
          acc[1][r] = fmaf(xv[r][kk], w1c, acc[1][r]);
          acc[2][r] = fmaf(xv[r][kk], w2c, acc[2][r]);
          acc[3][r] = fmaf(xv[r][kk], w3c, acc[3][r]);
        }
      }
    }
    __syncthreads();   // reads of h2/xs done before ys overlays smem
    #pragma unroll
    for (int oi = 0; oi < 4; ++oi) {
      float bb = b3[oc + 64 * oi];
      #pragma unroll
      for (int r = 0; r < 4; ++r)
        ys[(4 * rg + r) * 260 + oc + 64 * oi] = acc[oi][r] + bb;
    }
  }
  __syncthreads();

  // ---- iteration-invariant operand fragments ----
  short8 aah[2][8], aal[2][8];   // A rows 16T.., full K (both tiles per wave)
  f4v binit[2];
  #pragma unroll
  for (int T = 0; T < 2; ++T) {
    #pragma unroll
    for (int s = 0; s < 8; ++s) {
      const float* ap = A + (size_t)(l15 + 16 * T) * 256 + 32 * s + 8 * quad;
      float v[8];
      #pragma unroll
      for (int j = 0; j < 8; ++j) v[j] = ap[j];
      split8(v, aah[T][s], aal[T][s]);
    }
    f4v bv = *(const f4v*)&bmat[(size_t)(row0 + l15) * 32 + 16 * T + 4 * quad];
    binit[T] = -bv;
  }

  short8 kanh[4], kanl[4];       // KAT n-tiles U = 4wv..4wv+3
  #pragma unroll
  for (int u = 0; u < 4; ++u) {
    const int U = 4 * wv + u;
    const float* kp = KAT + (size_t)(16 * U + l15) * 32 + 8 * quad;
    float v[8];
    #pragma unroll
    for (int j = 0; j < 8; ++j) v[j] = kp[j];
    split8(v, kanh[u], kanl[u]);
  }

  // ---- zfrag write offsets (B-op fragment order; verified U-derived map) ---
  int zoff[4];
  #pragma unroll
  for (int u = 0; u < 4; ++u) {
    const int U = 4 * wv + u;
    const int qp = 2 * (U & 1) + (quad >> 1);
    zoff[u] = (((U >> 3) * 4 + ((U >> 1) & 3)) * 2) * 256
              + qp * 64 + l15 * 4 + 2 * (quad & 1);
  }

  // ---- init z regs from y; publish zfrag[0] (overlays MLP scratch) ----
  float zr[4][4];
  #pragma unroll
  for (int u = 0; u < 4; ++u) {
    const int U = 4 * wv + u;
    f4v yv = *(const f4v*)&ys[l15 * 260 + 16 * U + 4 * quad];
    #pragma unroll
    for (int r = 0; r < 4; ++r) zr[u][r] = yv[r];
  }
  __syncthreads();   // all ys reads done before zfrag overlays the region
  #pragma unroll
  for (int u = 0; u < 4; ++u) {
    unsigned h0, l0, h1_, l1_;
    split_pair(zr[u][0], zr[u][1], h0, l0);
    split_pair(zr[u][2], zr[u][3], h1_, l1_);
    u2v hv; hv[0] = h0; hv[1] = h1_;
    u2v lv; lv[0] = l0; lv[1] = l1_;
    *(u2v*)&zsm[zoff[u]] = hv;
    *(u2v*)&zsm[zoff[u] + 256] = lv;
  }
  __syncthreads();

  const int niter = n_iter_p[0];
  int p = 0;

  for (int it = 0; it <= niter; ++it) {
    const unsigned* zb = zsm + p * 4096;

    // ---- full-K r = A z^T - b  (each wave, both m-tiles; 48 MFMA) ----
    f4v c0[2], c1[2];
    c0[0] = binit[0]; c0[1] = binit[1];
    c1[0] = f4v{0.f, 0.f, 0.f, 0.f};
    c1[1] = f4v{0.f, 0.f, 0.f, 0.f};
    #pragma unroll
    for (int half = 0; half < 2; ++half) {
      short8 zfh[4], zfl[4];
      #pragma unroll
      for (int q4 = 0; q4 < 4; ++q4) {
        int s = 4 * half + q4;
        zfh[q4] = *(const short8*)&zb[(s * 2 + 0) * 256 + lane * 4];
        zfl[q4] = *(const short8*)&zb[(s * 2 + 1) * 256 + lane * 4];
      }
      #pragma unroll
      for (int q4 = 0; q4 < 4; ++q4) {
        int s = 4 * half + q4;
        #pragma unroll
        for (int T = 0; T < 2; ++T) {
          f4v cc = (q4 & 1) ? c1[T] : c0[T];
          cc = mfma16(aah[T][s], zfh[q4], cc);
          cc = mfma16(aal[T][s], zfh[q4], cc);
          cc = mfma16(aah[T][s], zfl[q4], cc);
          if (q4 & 1) c1[T] = cc; else c0[T] = cc;
        }
      }
    }
    // ---- wave-private round-trip: C-layout store, B-op load (no barrier) ---
    #pragma unroll
    for (int T = 0; T < 2; ++T) {
      f4v rA = c0[T] + c1[T];
      *(f4v*)&rb[l15 * 36 + 16 * T + 4 * quad] = rA;   // r[i][m], m=16T+4q+r
    }
    f4v ra = *(const f4v*)&rb[l15 * 36 + 8 * quad];       // m = 8q..8q+3
    f4v rbv = *(const f4v*)&rb[l15 * 36 + 8 * quad + 4];  // m = 8q+4..8q+7
    float rv[8] = {ra[0], ra[1], ra[2], ra[3], rbv[0], rbv[1], rbv[2], rbv[3]};
    short8 rh, rl;
    split8(rv, rh, rl);

    // ---- w^T = KAT r  for this wave's 4 U-tiles (12 MFMA) ----
    f4v cB[4];
    #pragma unroll
    for (int u = 0; u < 4; ++u) {
      f4v cc = {0.f, 0.f, 0.f, 0.f};
      cc = mfma16(kanh[u], rh, cc);
      cc = mfma16(kanl[u], rh, cc);
      cc = mfma16(kanh[u], rl, cc);
      cB[u] = cc;
    }

    if (it < niter) {
      unsigned* zw = zsm + (p ^ 1) * 4096;
      #pragma unroll
      for (int u = 0; u < 4; ++u) {
        #pragma unroll
        for (int r = 0; r < 4; ++r) {
          float z = zr[u][r], wvv = cB[u][r];
          float vv = fminf(fmaxf(z - 2.f * wvv, 0.f), 1.f);  // clip(2u - z)
          zr[u][r] = fmaf(1.7f, vv - z + wvv, z);            // z += 1.7*(v-u)
        }
        unsigned h0, l0, h1_, l1_;
        split_pair(zr[u][0], zr[u][1], h0, l0);
        split_pair(zr[u][2], zr[u][3], h1_, l1_);
        u2v hv; hv[0] = h0; hv[1] = h1_;
        u2v lv; lv[0] = l0; lv[1] = l1_;
        *(u2v*)&zw[zoff[u]] = hv;
        *(u2v*)&zw[zoff[u] + 256] = lv;
      }
      __syncthreads();           // the ONE barrier per iteration
      p ^= 1;
    } else {
      #pragma unroll
      for (int u = 0; u < 4; ++u) {
        const int U = 4 * wv + u;
        f4v ov;
        #pragma unroll
        for (int r = 0; r < 4; ++r) ov[r] = zr[u][r] - cB[u][r];
        *(f4v*)&out[(size_t)(row0 + l15) * 256 + 16 * U + 4 * quad] = ov;
      }
    }
  }
}

// ---------------------------------------------------------------------------
extern "C" void kernel_launch(void* const* d_in, const int* in_sizes, int n_in,
                              void* d_out, int out_size, void* d_ws, size_t ws_size,
                              hipStream_t stream) {
  const float* x    = (const float*)d_in[0];
  const float* bmat = (const float*)d_in[1];
  const float* W1   = (const float*)d_in[2];
  const float* b1   = (const float*)d_in[3];
  const float* W2   = (const float*)d_in[4];
  const float* b2   = (const float*)d_in[5];
  const float* W3   = (const float*)d_in[6];
  const float* b3   = (const float*)d_in[7];
  const float* A    = (const float*)d_in[8];
  const int*  n_it  = (const int*)d_in[10];
  float* KAT = (float*)d_ws;          // 256*32 floats = 32 KB
  float* out = (float*)d_out;

  hipLaunchKernelGGL(k_prep, dim3(1), dim3(256), 0, stream, A, KAT);
  hipLaunchKernelGGL(k_main, dim3(Bn / TR), dim3(256), 0, stream,
                     x, bmat, W1, b1, W2, b2, W3, b3, A, KAT, n_it, out);
}